// Round 9
// baseline (330.049 us; speedup 1.0000x reference)
//
#include <hip/hip_runtime.h>
#include <hip/hip_fp16.h>
#include <stdint.h>

#define OUT_F 4096
#define IN_F  4096
#define M_DIM 8192
#define K_DIM IN_F
#define N_DIM OUT_F
#define GROUPS (OUT_F * IN_F / 64)
#define NTRIP  (GROUPS * 8)
#define NPARAM (GROUPS * 2)

typedef __attribute__((ext_vector_type(4))) float f32x4;
typedef __attribute__((ext_vector_type(8))) short bf16x8;
typedef __attribute__((ext_vector_type(8))) unsigned short u16x8;

static __device__ __forceinline__ unsigned short f32_to_bf16(float f) {
    unsigned int u = __builtin_bit_cast(unsigned int, f);
    u += 0x7fffu + ((u >> 16) & 1u);
    return (unsigned short)(u >> 16);
}

// ---------------- params dtype detection (f16 vs f32 on device) ----------------
__global__ void flag_init(int* f) { f[0] = 0; }

__global__ __launch_bounds__(256) void detect_f16(const __half* __restrict__ p,
                                                  int* __restrict__ flag) {
    int big = 0;
    for (int i = blockIdx.x * 256 + threadIdx.x; i < NPARAM; i += 256 * 256) {
        float v = __half2float(p[i]);
        if (!(fabsf(v) < 1.0f)) big = 1;
    }
    if (big) atomicOr(flag, 1);
}

// ---------------- dequant: 3-bit packed -> bf16 W[N][K] row-major ----------------
__global__ __launch_bounds__(256) void dequant3(const int* __restrict__ pk,
                                                const void* __restrict__ params,
                                                const int* __restrict__ flag,
                                                unsigned short* __restrict__ W) {
    int t = blockIdx.x * 256 + threadIdx.x;
    int b0 = pk[3 * t + 0];
    int b1 = pk[3 * t + 1];
    int b2 = pk[3 * t + 2];
    int g = t >> 3;
    float lo, hi;
    if (flag[0] == 0) {
        const __half* p = (const __half*)params;
        lo = __half2float(p[2 * g + 0]);
        hi = __half2float(p[2 * g + 1]);
    } else {
        const float* p = (const float*)params;
        lo = p[2 * g + 0];
        hi = p[2 * g + 1];
    }
    float s = (hi - lo) * (1.0f / 7.0f);

    int q[8];
    q[0] = b0 & 7;
    q[1] = (b0 >> 3) & 7;
    q[2] = ((b0 >> 6) & 3) | ((b1 & 1) << 2);
    q[3] = (b1 >> 1) & 7;
    q[4] = (b1 >> 4) & 7;
    q[5] = ((b1 >> 7) & 1) | ((b2 & 3) << 1);
    q[6] = (b2 >> 2) & 7;
    q[7] = (b2 >> 5) & 7;

    u16x8 o;
#pragma unroll
    for (int j = 0; j < 8; j++) {
        float w = (float)q[j] * s + lo;
        o[j] = f32_to_bf16(w);
    }
    *(u16x8*)&W[8 * (size_t)t] = o;
}

// ---------------- x: f32 -> bf16 ----------------
__global__ __launch_bounds__(256) void cvt_x(const float* __restrict__ x,
                                             unsigned short* __restrict__ xb) {
    size_t t = (size_t)blockIdx.x * 256 + threadIdx.x;
    f32x4 a = *(const f32x4*)&x[8 * t];
    f32x4 b = *(const f32x4*)&x[8 * t + 4];
    u16x8 o;
#pragma unroll
    for (int j = 0; j < 4; j++) o[j] = f32_to_bf16(a[j]);
#pragma unroll
    for (int j = 0; j < 4; j++) o[4 + j] = f32_to_bf16(b[j]);
    *(u16x8*)&xb[8 * t] = o;
}

// ======== 256x128 GEMM, BK=32 windows, triple-buffer LDS, 2 blocks/CU ========
// R8 structure; LDS layout replaced with the PROVEN zero-conflict 128B-row
// XOR swizzle (R3/R4/R7: 0 conflicts measured). A 256x32 tile packs as
// 128 rows x 128B: chunk j of row r = A[r + 128*(j>>2)][(j&3)*8 ..+7];
// phys_chunk = logical_chunk ^ (r&7). B 128x32 -> 64 rows x 128B (half
// stride 64). Staging: linear LDS dest; lane-local j=(l&7)^(l>>3) folds
// into per-lane vbaseA/vbaseB. Reads: byte = (half*64+kg*16)^((fr&7)<<4),
// row fr*128 — bitwise identical to R4's bank-verified pattern.
// Window kb: {read F_next <- tile kb+1; stage tile kb+3 -> buf[kb%3];
//             MFMA(F_cur); lgkm(0); vmcnt(6); barrier}.

#define LGKM0 asm volatile("s_waitcnt lgkmcnt(0)" ::: "memory")
#define VMW(n) asm volatile("s_waitcnt vmcnt(" #n ")" ::: "memory")
#define BAR() asm volatile("s_barrier" ::: "memory")

#define GLO(gp, lp) __builtin_amdgcn_global_load_lds( \
    (const __attribute__((address_space(1))) unsigned int*)(gp), \
    (__attribute__((address_space(3))) unsigned int*)(lp), 16, 0, 0)

// read 8 A-frags + 4 B-frags (one K=32 tile) into set F
#define READ12(F, roff) do { \
  _Pragma("unroll") for (int m_ = 0; m_ < 8; ++m_) \
    F##A[m_] = *(const bf16x8*)(shb + (roff) + frA + m_ * 2048); \
  _Pragma("unroll") for (int n_ = 0; n_ < 4; ++n_) \
    F##B[n_] = *(const bf16x8*)(shb + (roff) + 16384 + frB + n_ * 2048); \
} while (0)

#define MFMA32(F) do { __builtin_amdgcn_s_setprio(1); \
  _Pragma("unroll") for (int m_ = 0; m_ < 8; ++m_) \
  _Pragma("unroll") for (int n_ = 0; n_ < 4; ++n_) \
    acc[m_][n_] = __builtin_amdgcn_mfma_f32_16x16x32_bf16(F##A[m_], F##B[n_], acc[m_][n_], 0, 0, 0); \
  __builtin_amdgcn_s_setprio(0); } while (0)

// stage one K=32 tile: A 128 LDS rows (4 rounds of 32) + B 64 rows (2 rounds)
#define STAGE(soff, kt) do { \
  _Pragma("unroll") for (int c_ = 0; c_ < 4; ++c_) \
    GLO(GAb + (size_t)(kt) * 64 + c_ * 262144 + vbaseA, shw + (soff) + c_ * 4096 + w4 * 1024); \
  _Pragma("unroll") for (int c_ = 0; c_ < 2; ++c_) \
    GLO(GBb + (size_t)(kt) * 64 + c_ * 262144 + vbaseB, shw + (soff) + 16384 + c_ * 4096 + w4 * 1024); \
} while (0)

__global__ __launch_bounds__(256, 2) void gemm_tb(const unsigned short* __restrict__ A,
                                                  const unsigned short* __restrict__ B,
                                                  const float* __restrict__ bias,
                                                  float* __restrict__ C) {
    __shared__ unsigned short sh[3 * 12288];     // 72 KiB: 3 bufs x (A 16K + B 8K)

    // bijective XCD swizzle: nwg = 1024, cpx = 128
    int bid = blockIdx.x;
    int swz = (bid & 7) * 128 + (bid >> 3);
    int bm = swz >> 5, bn = swz & 31;            // 32 x 32 tiles
    const int row0 = bm * 256, col0 = bn * 128;

    const int t = threadIdx.x;
    const int lane = t & 63;
    const int w4 = t >> 6;                       // wave 0..3
    const int wm = w4 >> 1, wn = w4 & 1;         // 2x2 waves, each 128x64

    // ---- staging source addressing (lane-local, loop-invariant) ----
    // dest = linear: lane l -> LDS row (w4*8 + (l>>3)) + 32*c_, phys chunk l&7.
    // logical chunk j = (l&7) ^ (l>>3)  [since (row&7) == l>>3].
    const int jl = (lane & 7) ^ (lane >> 3);
    const int lrow = (lane >> 3);                // row within wave's 8-row slab
    const int vbaseA = (w4 * 8 + lrow + 128 * (jl >> 2)) * 8192 + (jl & 3) * 16;
    const int vbaseB = (w4 * 8 + lrow +  64 * (jl >> 2)) * 8192 + (jl & 3) * 16;

    // ---- fragment read addressing (R4-verified bank pattern) ----
    const int fr = lane & 15;
    const int kg = lane >> 4;
    const int swzb = (fr & 7) << 4;
    const int frA = fr * 128 + ((wm * 64 + kg * 16) ^ swzb);
    const int frB = fr * 128 + ((wn * 64 + kg * 16) ^ swzb);

    const char* GAb = (const char*)A + (size_t)row0 * 8192;
    const char* GBb = (const char*)B + (size_t)col0 * 8192;
    const char* shb = (const char*)sh;
    char* shw = (char*)sh;

    f32x4 acc[8][4] = {};
    bf16x8 FaA[8], FaB[4], FbA[8], FbB[4];

    // prologue: stage tiles 0,1,2 into bufs 0,1,2; publish t0,t1; prime Fa<-t0
    STAGE(0, 0); STAGE(24576, 1); STAGE(49152, 2);
    VMW(6);                    // t0,t1 complete; t2 in flight
    BAR();
    READ12(Fa, 0);
    LGKM0;
    BAR();                     // protect prime-read from window-0's stage(buf0)

    int r0 = 0, r1 = 24576, r2 = 49152;          // bufs (kb%3,(kb+1)%3,(kb+2)%3)

    for (int j = 0; j < 61; ++j) {
        const int kb = 2 * j;
        // window kb (even): cur Fa; read Fb <- tile kb+1; stage kb+3 -> buf[kb%3]
        READ12(Fb, r1);
        STAGE(r0, kb + 3);
        MFMA32(Fa);
        LGKM0; VMW(6); BAR();
        // window kb+1 (odd): cur Fb; read Fa <- tile kb+2; stage kb+4
        READ12(Fa, r2);
        STAGE(r1, kb + 4);
        MFMA32(Fb);
        LGKM0; VMW(6); BAR();
        int tmp = r0; r0 = r2; r2 = r1; r1 = tmp;   // advance by 2 windows
    }
    // windows 122..127 peeled (last stage at 124 -> tile 127)
    READ12(Fb, r1); STAGE(r0, 125); MFMA32(Fa); LGKM0; VMW(6); BAR();   // w122
    READ12(Fa, r2); STAGE(r1, 126); MFMA32(Fb); LGKM0; VMW(6); BAR();   // w123
    { int tmp = r0; r0 = r2; r2 = r1; r1 = tmp; }
    READ12(Fb, r1); STAGE(r0, 127); MFMA32(Fa); LGKM0; VMW(6); BAR();   // w124
    READ12(Fa, r2);                 MFMA32(Fb); LGKM0; VMW(0); BAR();   // w125
    READ12(Fb, r0);                 MFMA32(Fa); LGKM0; BAR();           // w126
    MFMA32(Fb);                                                         // w127

    // epilogue: C/D layout col=lane&15, row=(lane>>4)*4+j; fuse bias
    const int crow = kg * 4;
    const int ccol = fr;
#pragma unroll
    for (int mi = 0; mi < 8; ++mi) {
#pragma unroll
        for (int ni = 0; ni < 4; ++ni) {
            int col = col0 + wn * 64 + ni * 16 + ccol;
            float bv = bias[col];
#pragma unroll
            for (int jj = 0; jj < 4; ++jj) {
                int rw = row0 + wm * 128 + mi * 16 + crow + jj;
                C[(size_t)rw * N_DIM + col] = acc[mi][ni][jj] + bv;
            }
        }
    }
}

__global__ void ws_guard(float* out, float v) { out[0] = v; }

extern "C" void kernel_launch(void* const* d_in, const int* in_sizes, int n_in,
                              void* d_out, int out_size, void* d_ws, size_t ws_size,
                              hipStream_t stream) {
    const float* x      = (const float*)d_in[0];
    const int*   pk     = (const int*)d_in[1];
    const void*  params = (const void*)d_in[2];
    const float* bias   = (const float*)d_in[3];
    float* out = (float*)d_out;

    const size_t needW = (size_t)OUT_F * IN_F * 2;
    const size_t needX = (size_t)M_DIM * IN_F * 2;
    const size_t needF = 256;
    if (ws_size < needW + needX + needF) {
        ws_guard<<<1, 1, 0, stream>>>(out, 1.0e6f + (float)(ws_size >> 20));
        return;
    }
    unsigned short* W  = (unsigned short*)d_ws;
    unsigned short* Xb = (unsigned short*)((char*)d_ws + needW);
    int*            fl = (int*)((char*)d_ws + needW + needX);

    flag_init<<<1, 1, 0, stream>>>(fl);
    detect_f16<<<256, 256, 0, stream>>>((const __half*)params, fl);
    dequant3<<<NTRIP / 256, 256, 0, stream>>>(pk, params, fl, W);
    cvt_x<<<(int)(((size_t)M_DIM * IN_F / 8) / 256), 256, 0, stream>>>(x, Xb);
    gemm_tb<<<(M_DIM / 256) * (N_DIM / 128), 256, 0, stream>>>(Xb, W, bias, out);
}

// Round 10
// 326.685 us; speedup vs baseline: 1.0103x; 1.0103x over previous
//
#include <hip/hip_runtime.h>
#include <hip/hip_fp16.h>
#include <stdint.h>

#define OUT_F 4096
#define IN_F  4096
#define M_DIM 8192
#define K_DIM IN_F
#define N_DIM OUT_F
#define GROUPS (OUT_F * IN_F / 64)
#define NTRIP  (GROUPS * 8)
#define NPARAM (GROUPS * 2)
#define NKT    (K_DIM / 64)      // 64 K-tiles (BK=64)
#define NIT    (NKT / 2)         // 32 iterations

typedef __attribute__((ext_vector_type(4)))  float f32x4;
typedef __attribute__((ext_vector_type(16))) float f32x16;
typedef __attribute__((ext_vector_type(8)))  short bf16x8;
typedef __attribute__((ext_vector_type(8)))  unsigned short u16x8;

static __device__ __forceinline__ unsigned short f32_to_bf16(float f) {
    unsigned int u = __builtin_bit_cast(unsigned int, f);
    u += 0x7fffu + ((u >> 16) & 1u);
    return (unsigned short)(u >> 16);
}

// ---------------- params dtype detection (f16 vs f32 on device) ----------------
__global__ void flag_init(int* f) { f[0] = 0; }

__global__ __launch_bounds__(256) void detect_f16(const __half* __restrict__ p,
                                                  int* __restrict__ flag) {
    int big = 0;
    for (int i = blockIdx.x * 256 + threadIdx.x; i < NPARAM; i += 256 * 256) {
        float v = __half2float(p[i]);
        if (!(fabsf(v) < 1.0f)) big = 1;
    }
    if (big) atomicOr(flag, 1);
}

// ---------------- dequant: 3-bit packed -> bf16 W[N][K] row-major ----------------
__global__ __launch_bounds__(256) void dequant3(const int* __restrict__ pk,
                                                const void* __restrict__ params,
                                                const int* __restrict__ flag,
                                                unsigned short* __restrict__ W) {
    int t = blockIdx.x * 256 + threadIdx.x;
    int b0 = pk[3 * t + 0];
    int b1 = pk[3 * t + 1];
    int b2 = pk[3 * t + 2];
    int g = t >> 3;
    float lo, hi;
    if (flag[0] == 0) {
        const __half* p = (const __half*)params;
        lo = __half2float(p[2 * g + 0]);
        hi = __half2float(p[2 * g + 1]);
    } else {
        const float* p = (const float*)params;
        lo = p[2 * g + 0];
        hi = p[2 * g + 1];
    }
    float s = (hi - lo) * (1.0f / 7.0f);

    int q[8];
    q[0] = b0 & 7;
    q[1] = (b0 >> 3) & 7;
    q[2] = ((b0 >> 6) & 3) | ((b1 & 1) << 2);
    q[3] = (b1 >> 1) & 7;
    q[4] = (b1 >> 4) & 7;
    q[5] = ((b1 >> 7) & 1) | ((b2 & 3) << 1);
    q[6] = (b2 >> 2) & 7;
    q[7] = (b2 >> 5) & 7;

    u16x8 o;
#pragma unroll
    for (int j = 0; j < 8; j++) {
        float w = (float)q[j] * s + lo;
        o[j] = f32_to_bf16(w);
    }
    *(u16x8*)&W[8 * (size_t)t] = o;
}

// ---------------- x: f32 -> bf16 ----------------
__global__ __launch_bounds__(256) void cvt_x(const float* __restrict__ x,
                                             unsigned short* __restrict__ xb) {
    size_t t = (size_t)blockIdx.x * 256 + threadIdx.x;
    f32x4 a = *(const f32x4*)&x[8 * t];
    f32x4 b = *(const f32x4*)&x[8 * t + 4];
    u16x8 o;
#pragma unroll
    for (int j = 0; j < 4; j++) o[j] = f32_to_bf16(a[j]);
#pragma unroll
    for (int j = 0; j < 4; j++) o[4 + j] = f32_to_bf16(b[j]);
    *(u16x8*)&xb[8 * t] = o;
}

// ====== 256x256 8-phase GEMM (R4-proven schedule) on mfma_32x32x16_bf16 ======
// 8 waves (2M x 4N), per-wave 128x64 = acc[4][2] of f32x16 (128 AGPR).
// MFMA 32x32x16: lane l holds A[l&31][ks*16+(l>>5)*8+j]; B mirrored; C/D per
// m74/m101: col=lane&31, row=(reg&3)+8*(reg>>2)+4*(lane>>5).
// LDS 128 KiB, 64B-ROW bank layout per operand tile (256 rows x 64 k bf16):
//   p = r + 256*(k>=32); slot = ((k>>3)&3) ^ ((r>>1)&3); byte = p*64+slot*16.
// 32-lane row-span reads land 8 lanes per 4-bank group = conflict-free floor.
// Staging: linear gload_lds dest; inverse perm folded into per-lane vbase.
// Schedule/stages/vmcnt = R4 verbatim (ph1 Y.B, ph4 X'.A+VMW(4), ph5 X'.B,
// ph8 Y'.A+VMW(4); tail VMW(0)).

#define BAR() asm volatile("s_barrier" ::: "memory")
#define VMW(n) asm volatile("s_waitcnt vmcnt(" #n ")" ::: "memory")
#define GLO(gp, lp) __builtin_amdgcn_global_load_lds( \
    (const __attribute__((address_space(1))) unsigned int*)(gp), \
    (__attribute__((address_space(3))) unsigned int*)(lp), 16, 0, 0)

#define READ_A8(buf, a) do { _Pragma("unroll") for (int m2_ = 0; m2_ < 2; ++m2_) \
  _Pragma("unroll") for (int ks_ = 0; ks_ < 4; ++ks_) \
    af[m2_][ks_] = *(const bf16x8*)(shb + (buf) * 65536 + frA + (a) * 4096 + m2_ * 2048 \
                                    + (ks_ >> 1) * 16384 + ((ks_ & 1) ? sO16 : sE16)); } while (0)

#define READ_B4(buf, ni) do { _Pragma("unroll") for (int ks_ = 0; ks_ < 4; ++ks_) \
    bfr[ks_] = *(const bf16x8*)(shb + (buf) * 65536 + frB + (ni) * 2048 \
                                + (ks_ >> 1) * 16384 + ((ks_ & 1) ? sO16 : sE16)); } while (0)

#define MFMA_Q8(a, ni) do { __builtin_amdgcn_s_setprio(1); \
  _Pragma("unroll") for (int ks_ = 0; ks_ < 4; ++ks_) \
  _Pragma("unroll") for (int m2_ = 0; m2_ < 2; ++m2_) \
    acc[(a) * 2 + m2_][ni] = __builtin_amdgcn_mfma_f32_32x32x16_bf16(af[m2_][ks_], bfr[ks_], acc[(a) * 2 + m2_][ni], 0, 0, 0); \
  __builtin_amdgcn_s_setprio(0); } while (0)

// stage one 256x64 operand tile (4 gload_lds, 8KB each)
#define STAGE_T(bufbyte, Gb, kt) do { \
  _Pragma("unroll") for (int h_ = 0; h_ < 2; ++h_) \
  _Pragma("unroll") for (int p_ = 0; p_ < 2; ++p_) \
    GLO((Gb) + (size_t)(kt) * 128 + h_ * 64 + p_ * 1048576 + vbase, \
        shw + (bufbyte) + h_ * 16384 + p_ * 8192 + w * 1024); } while (0)

__global__ __launch_bounds__(512, 1) void gemm32(const unsigned short* __restrict__ A,
                                                 const unsigned short* __restrict__ B,
                                                 const float* __restrict__ bias,
                                                 float* __restrict__ C) {
    __shared__ unsigned short sh[65536];         // 128 KiB: buf*65536B, B at +32768B

    int bid = blockIdx.x;
    int swz = (bid & 7) * 64 + (bid >> 3);       // bijective XCD swizzle (nwg=512)
    int bm = swz >> 4, bn = swz & 15;            // 32 x 16 tiles
    const int row0 = bm * 256, col0 = bn * 256;

    const int t = threadIdx.x;
    const int lane = t & 63;
    const int w = t >> 6;
    const int wm = w >> 2, wn = w & 3;           // 2 x 4 waves, each 128x64

    // staging source pre-permutation (lane-local): dest linear d=...+lane*16
    // -> r = p*128 + w*16 + (lane>>2), kg2 = (lane&3)^((lane>>3)&3), khigh=h
    const int vbase = (w * 16 + (lane >> 2)) * 8192 + (((lane & 3) ^ ((lane >> 3) & 3)) << 4);

    // fragment read addressing
    const int lr  = lane & 31;
    const int lhi = lane >> 5;
    const int lsb = (lane >> 1) & 3;             // (r>>1)&3 contribution
    const int sE16 = (lhi ^ lsb) << 4;           // slot for even ks
    const int sO16 = ((2 + lhi) ^ lsb) << 4;     // slot for odd ks
    const int frA = (wm * 128 + lr) * 64;
    const int frB = 32768 + (wn * 64 + lr) * 64;

    const char* GAb = (const char*)A + (size_t)row0 * 8192;
    const char* GBb = (const char*)B + (size_t)col0 * 8192;
    const char* shb = (const char*)sh;
    char* shw = (char*)sh;

    f32x16 acc[4][2] = {};                       // [mi 32-row tile][ni 32-col tile]
    bf16x8 af[2][4], bfr[4];

    // prologue: X(buf0) <- tile0 A,B ; Y(buf1) <- tile1 A   (12 loads)
    STAGE_T(0, GAb, 0);
    STAGE_T(32768, GBb, 0);
    STAGE_T(65536, GAb, 1);
    VMW(4);                    // X complete; Y.A in flight
    BAR();

    for (int it = 0; it < NIT; ++it) {
        const int ktx = 2 * it;
        const bool pf = (it + 1 < NIT);

        // ph1: X q(a0,n0); stage Y.B <- tile ktx+1
        READ_A8(0, 0); READ_B4(0, 0);
        STAGE_T(65536 + 32768, GBb, ktx + 1);
        BAR(); MFMA_Q8(0, 0); BAR();
        // ph2: X q(a0,n1)
        READ_B4(0, 1);
        BAR(); MFMA_Q8(0, 1); BAR();
        // ph3: X q(a1,n1)
        READ_A8(0, 1);
        BAR(); MFMA_Q8(1, 1); BAR();
        // ph4: X q(a1,n0); stage X'.A; counted vmcnt
        READ_B4(0, 0);
        if (pf) { STAGE_T(0, GAb, ktx + 2); VMW(4); }
        else    { VMW(0); }
        BAR(); MFMA_Q8(1, 0); BAR();
        // ph5: Y q(a0,n0); stage X'.B
        READ_A8(1, 0); READ_B4(1, 0);
        if (pf) STAGE_T(32768, GBb, ktx + 2);
        BAR(); MFMA_Q8(0, 0); BAR();
        // ph6: Y q(a0,n1)
        READ_B4(1, 1);
        BAR(); MFMA_Q8(0, 1); BAR();
        // ph7: Y q(a1,n1)
        READ_A8(1, 1);
        BAR(); MFMA_Q8(1, 1); BAR();
        // ph8: Y q(a1,n0); stage Y'.A; counted vmcnt
        READ_B4(1, 0);
        if (pf) { STAGE_T(65536, GAb, ktx + 3); VMW(4); }
        else    { VMW(0); }
        BAR(); MFMA_Q8(1, 0); BAR();
    }

    // epilogue: C/D 32x32 layout col=lane&31, row=(reg&3)+8*(reg>>2)+4*lhi
#pragma unroll
    for (int mi = 0; mi < 4; ++mi) {
#pragma unroll
        for (int ni = 0; ni < 2; ++ni) {
            int col = col0 + wn * 64 + ni * 32 + lr;
            float bv = bias[col];
#pragma unroll
            for (int j = 0; j < 16; ++j) {
                int rw = row0 + wm * 128 + mi * 32 + (j & 3) + 8 * (j >> 2) + 4 * lhi;
                C[(size_t)rw * N_DIM + col] = acc[mi][ni][j] + bv;
            }
        }
    }
}

__global__ void ws_guard(float* out, float v) { out[0] = v; }

extern "C" void kernel_launch(void* const* d_in, const int* in_sizes, int n_in,
                              void* d_out, int out_size, void* d_ws, size_t ws_size,
                              hipStream_t stream) {
    const float* x      = (const float*)d_in[0];
    const int*   pk     = (const int*)d_in[1];
    const void*  params = (const void*)d_in[2];
    const float* bias   = (const float*)d_in[3];
    float* out = (float*)d_out;

    const size_t needW = (size_t)OUT_F * IN_F * 2;
    const size_t needX = (size_t)M_DIM * IN_F * 2;
    const size_t needF = 256;
    if (ws_size < needW + needX + needF) {
        ws_guard<<<1, 1, 0, stream>>>(out, 1.0e6f + (float)(ws_size >> 20));
        return;
    }
    unsigned short* W  = (unsigned short*)d_ws;
    unsigned short* Xb = (unsigned short*)((char*)d_ws + needW);
    int*            fl = (int*)((char*)d_ws + needW + needX);

    flag_init<<<1, 1, 0, stream>>>(fl);
    detect_f16<<<256, 256, 0, stream>>>((const __half*)params, fl);
    dequant3<<<NTRIP / 256, 256, 0, stream>>>(pk, params, fl, W);
    cvt_x<<<(int)(((size_t)M_DIM * IN_F / 8) / 256), 256, 0, stream>>>(x, Xb);
    gemm32<<<(M_DIM / 256) * (N_DIM / 256), 512, 0, stream>>>(Xb, W, bias, out);
}

// Round 11
// 323.860 us; speedup vs baseline: 1.0191x; 1.0087x over previous
//
#include <hip/hip_runtime.h>
#include <hip/hip_fp16.h>
#include <stdint.h>

#define OUT_F 4096
#define IN_F  4096
#define M_DIM 8192
#define K_DIM IN_F
#define N_DIM OUT_F
#define GROUPS (OUT_F * IN_F / 64)
#define NTRIP  (GROUPS * 8)
#define NPARAM (GROUPS * 2)
#define NKT    (K_DIM / 64)      // 64 K-tiles (BK=64)
#define NIT    (NKT / 2)         // 32 iterations

typedef __attribute__((ext_vector_type(4)))  float f32x4;
typedef __attribute__((ext_vector_type(16))) float f32x16;
typedef __attribute__((ext_vector_type(8)))  short bf16x8;
typedef __attribute__((ext_vector_type(8)))  unsigned short u16x8;

static __device__ __forceinline__ unsigned short f32_to_bf16(float f) {
    unsigned int u = __builtin_bit_cast(unsigned int, f);
    u += 0x7fffu + ((u >> 16) & 1u);
    return (unsigned short)(u >> 16);
}

// ---------------- params dtype detection (f16 vs f32 on device) ----------------
__global__ void flag_init(int* f) { f[0] = 0; }

__global__ __launch_bounds__(256) void detect_f16(const __half* __restrict__ p,
                                                  int* __restrict__ flag) {
    int big = 0;
    for (int i = blockIdx.x * 256 + threadIdx.x; i < NPARAM; i += 256 * 256) {
        float v = __half2float(p[i]);
        if (!(fabsf(v) < 1.0f)) big = 1;
    }
    if (big) atomicOr(flag, 1);
}

// ---------------- dequant: 3-bit packed -> bf16 W[N][K] row-major ----------------
__global__ __launch_bounds__(256) void dequant3(const int* __restrict__ pk,
                                                const void* __restrict__ params,
                                                const int* __restrict__ flag,
                                                unsigned short* __restrict__ W) {
    int t = blockIdx.x * 256 + threadIdx.x;
    int b0 = pk[3 * t + 0];
    int b1 = pk[3 * t + 1];
    int b2 = pk[3 * t + 2];
    int g = t >> 3;
    float lo, hi;
    if (flag[0] == 0) {
        const __half* p = (const __half*)params;
        lo = __half2float(p[2 * g + 0]);
        hi = __half2float(p[2 * g + 1]);
    } else {
        const float* p = (const float*)params;
        lo = p[2 * g + 0];
        hi = p[2 * g + 1];
    }
    float s = (hi - lo) * (1.0f / 7.0f);

    int q[8];
    q[0] = b0 & 7;
    q[1] = (b0 >> 3) & 7;
    q[2] = ((b0 >> 6) & 3) | ((b1 & 1) << 2);
    q[3] = (b1 >> 1) & 7;
    q[4] = (b1 >> 4) & 7;
    q[5] = ((b1 >> 7) & 1) | ((b2 & 3) << 1);
    q[6] = (b2 >> 2) & 7;
    q[7] = (b2 >> 5) & 7;

    u16x8 o;
#pragma unroll
    for (int j = 0; j < 8; j++) {
        float w = (float)q[j] * s + lo;
        o[j] = f32_to_bf16(w);
    }
    *(u16x8*)&W[8 * (size_t)t] = o;
}

// ---------------- x: f32 -> bf16 ----------------
__global__ __launch_bounds__(256) void cvt_x(const float* __restrict__ x,
                                             unsigned short* __restrict__ xb) {
    size_t t = (size_t)blockIdx.x * 256 + threadIdx.x;
    f32x4 a = *(const f32x4*)&x[8 * t];
    f32x4 b = *(const f32x4*)&x[8 * t + 4];
    u16x8 o;
#pragma unroll
    for (int j = 0; j < 4; j++) o[j] = f32_to_bf16(a[j]);
#pragma unroll
    for (int j = 0; j < 4; j++) o[4 + j] = f32_to_bf16(b[j]);
    *(u16x8*)&xb[8 * t] = o;
}

// ====== 256x256 8-phase GEMM on mfma_32x32x16_bf16, PROVEN LDS layout ======
// R10 schedule (= R4's verbatim), LDS layout reverted to the measured-zero-
// conflict one (R3/R4/R9): tile = 256 rows x 128B (64 k bf16), XOR swizzle
// phys_16B_slot = logical_slot ^ (row&7). Staging identical to R4 (linear
// gload_lds dest; source col pre-XORed per lane). 32x32 fragment reads:
// lane l: rows lr=l&31, col_byte = (ks<<5) ^ cbx, cbx = (lhi<<4)^((lr&7)<<4);
// consecutive 8-lane groups sweep all 8 slots -> all 32 banks (R4-equivalent).
// C/D per m74/m101: col=lane&31, row=(reg&3)+8*(reg>>2)+4*(lane>>5).

#define BAR() asm volatile("s_barrier" ::: "memory")
#define VMW(n) asm volatile("s_waitcnt vmcnt(" #n ")" ::: "memory")
#define GLO(gp, lp) __builtin_amdgcn_global_load_lds( \
    (const __attribute__((address_space(1))) unsigned int*)(gp), \
    (__attribute__((address_space(3))) unsigned int*)(lp), 16, 0, 0)

#define READ_A8(buf, a) do { _Pragma("unroll") for (int m2_ = 0; m2_ < 2; ++m2_) \
  _Pragma("unroll") for (int ks_ = 0; ks_ < 4; ++ks_) \
    af[m2_][ks_] = *(const bf16x8*)(shb + (buf) * 65536 + frA + (a) * 8192 + m2_ * 4096 \
                                    + ((ks_ << 5) ^ cbx)); } while (0)

#define READ_B4(buf, ni) do { _Pragma("unroll") for (int ks_ = 0; ks_ < 4; ++ks_) \
    bfr[ks_] = *(const bf16x8*)(shb + (buf) * 65536 + 32768 + frB + (ni) * 4096 \
                                + ((ks_ << 5) ^ cbx)); } while (0)

#define MFMA_Q8(a, ni) do { __builtin_amdgcn_s_setprio(1); \
  _Pragma("unroll") for (int ks_ = 0; ks_ < 4; ++ks_) \
  _Pragma("unroll") for (int m2_ = 0; m2_ < 2; ++m2_) \
    acc[(a) * 2 + m2_][ni] = __builtin_amdgcn_mfma_f32_32x32x16_bf16(af[m2_][ks_], bfr[ks_], acc[(a) * 2 + m2_][ni], 0, 0, 0); \
  __builtin_amdgcn_s_setprio(0); } while (0)

// stage one 256x64 operand tile (4 gload_lds of 64 rows x 128B, R4 verbatim)
#define STAGE_T(bufbyte, Gb, kt) do { \
  _Pragma("unroll") for (int h_ = 0; h_ < 2; ++h_) \
  _Pragma("unroll") for (int p_ = 0; p_ < 2; ++p_) \
    GLO((Gb) + (size_t)(kt) * 128 + (size_t)((h_ * 128 + p_ * 64) * 8192) + voff, \
        shw + (bufbyte) + h_ * 16384 + p_ * 8192 + w * 1024); } while (0)

__global__ __launch_bounds__(512, 1) void gemm32(const unsigned short* __restrict__ A,
                                                 const unsigned short* __restrict__ B,
                                                 const float* __restrict__ bias,
                                                 float* __restrict__ C) {
    __shared__ unsigned short sh[65536];         // 128 KiB: 2 bufs x (A 32K + B 32K)

    int bid = blockIdx.x;
    int swz = (bid & 7) * 64 + (bid >> 3);       // bijective XCD swizzle (nwg=512)
    int bm = swz >> 4, bn = swz & 15;            // 32 x 16 tiles
    const int row0 = bm * 256, col0 = bn * 256;

    const int t = threadIdx.x;
    const int lane = t & 63;
    const int w = t >> 6;
    const int wm = w >> 2, wn = w & 3;           // 2 x 4 waves, each 128x64

    // staging (R4 verbatim): dest linear, source col pre-XORed
    const int l_hi = lane >> 3, l_lo = lane & 7;
    const int voff = (w * 8 + l_hi) * 8192 + ((l_lo ^ l_hi) * 16);

    // fragment read addressing (proven 128B-row swizzle)
    const int lr  = lane & 31;
    const int lhi = lane >> 5;
    const int cbx = (lhi << 4) ^ ((lr & 7) << 4);
    const int frA = (wm * 128 + lr) * 128;
    const int frB = (wn * 64 + lr) * 128;

    const char* GAb = (const char*)A + (size_t)row0 * 8192;
    const char* GBb = (const char*)B + (size_t)col0 * 8192;
    const char* shb = (const char*)sh;
    char* shw = (char*)sh;

    f32x16 acc[4][2] = {};                       // [mi 32-row tile][ni 32-col tile]
    bf16x8 af[2][4], bfr[4];

    // prologue: X(buf0) <- tile0 A,B ; Y(buf1) <- tile1 A   (12 loads)
    STAGE_T(0, GAb, 0);
    STAGE_T(32768, GBb, 0);
    STAGE_T(65536, GAb, 1);
    VMW(4);                    // X complete; Y.A in flight
    BAR();

    for (int it = 0; it < NIT; ++it) {
        const int ktx = 2 * it;
        const bool pf = (it + 1 < NIT);

        // ph1: X q(a0,n0); stage Y.B <- tile ktx+1
        READ_A8(0, 0); READ_B4(0, 0);
        STAGE_T(65536 + 32768, GBb, ktx + 1);
        BAR(); MFMA_Q8(0, 0); BAR();
        // ph2: X q(a0,n1)
        READ_B4(0, 1);
        BAR(); MFMA_Q8(0, 1); BAR();
        // ph3: X q(a1,n1)
        READ_A8(0, 1);
        BAR(); MFMA_Q8(1, 1); BAR();
        // ph4: X q(a1,n0); stage X'.A; counted vmcnt
        READ_B4(0, 0);
        if (pf) { STAGE_T(0, GAb, ktx + 2); VMW(4); }
        else    { VMW(0); }
        BAR(); MFMA_Q8(1, 0); BAR();
        // ph5: Y q(a0,n0); stage X'.B
        READ_A8(1, 0); READ_B4(1, 0);
        if (pf) STAGE_T(32768, GBb, ktx + 2);
        BAR(); MFMA_Q8(0, 0); BAR();
        // ph6: Y q(a0,n1)
        READ_B4(1, 1);
        BAR(); MFMA_Q8(0, 1); BAR();
        // ph7: Y q(a1,n1)
        READ_A8(1, 1);
        BAR(); MFMA_Q8(1, 1); BAR();
        // ph8: Y q(a1,n0); stage Y'.A; counted vmcnt
        READ_B4(1, 0);
        if (pf) { STAGE_T(65536, GAb, ktx + 3); VMW(4); }
        else    { VMW(0); }
        BAR(); MFMA_Q8(1, 0); BAR();
    }

    // epilogue: C/D 32x32 layout col=lane&31, row=(reg&3)+8*(reg>>2)+4*lhi
#pragma unroll
    for (int mi = 0; mi < 4; ++mi) {
#pragma unroll
        for (int ni = 0; ni < 2; ++ni) {
            int col = col0 + wn * 64 + ni * 32 + lr;
            float bv = bias[col];
#pragma unroll
            for (int j = 0; j < 16; ++j) {
                int rw = row0 + wm * 128 + mi * 32 + (j & 3) + 8 * (j >> 2) + 4 * lhi;
                C[(size_t)rw * N_DIM + col] = acc[mi][ni][j] + bv;
            }
        }
    }
}

__global__ void ws_guard(float* out, float v) { out[0] = v; }

extern "C" void kernel_launch(void* const* d_in, const int* in_sizes, int n_in,
                              void* d_out, int out_size, void* d_ws, size_t ws_size,
                              hipStream_t stream) {
    const float* x      = (const float*)d_in[0];
    const int*   pk     = (const int*)d_in[1];
    const void*  params = (const void*)d_in[2];
    const float* bias   = (const float*)d_in[3];
    float* out = (float*)d_out;

    const size_t needW = (size_t)OUT_F * IN_F * 2;
    const size_t needX = (size_t)M_DIM * IN_F * 2;
    const size_t needF = 256;
    if (ws_size < needW + needX + needF) {
        ws_guard<<<1, 1, 0, stream>>>(out, 1.0e6f + (float)(ws_size >> 20));
        return;
    }
    unsigned short* W  = (unsigned short*)d_ws;
    unsigned short* Xb = (unsigned short*)((char*)d_ws + needW);
    int*            fl = (int*)((char*)d_ws + needW + needX);

    flag_init<<<1, 1, 0, stream>>>(fl);
    detect_f16<<<256, 256, 0, stream>>>((const __half*)params, fl);
    dequant3<<<NTRIP / 256, 256, 0, stream>>>(pk, params, fl, W);
    cvt_x<<<(int)(((size_t)M_DIM * IN_F / 8) / 256), 256, 0, stream>>>(x, Xb);
    gemm32<<<(M_DIM / 256) * (N_DIM / 256), 512, 0, stream>>>(Xb, W, bias, out);
}